// Round 10
// baseline (238.517 us; speedup 1.0000x reference)
//
#include <hip/hip_runtime.h>
#include <math.h>
#include <float.h>

// Problem dims (fixed by setup_inputs)
#define BB 32
#define TT 2048
#define OO 128
#define CC 80
#define EPSF 1e-7f
#define NT 256            // LSA block size
#define NTP 1024          // producer block size (8 thr/token -> 8 waves/SIMD, HW max)
#define SLOTS 8           // columns per thread in LSA
#define CPAD 81           // LDS class-row stride: 81%32=17, gcd(17,32)=1 -> conflict-free
#define TPT 128           // tokens per cost tile
#define NTILE 16          // cost t-tiles (TT/TPT)

typedef float vf4 __attribute__((ext_vector_type(4)));   // native vec for nontemporal
typedef unsigned long long u64;

struct alignas(16) URow { double u; int row; int pad; };   // {u[row4col[j]], row4col[j]}
struct alignas(8)  P2   { int i; int j; };                 // path row, its prior column
struct alignas(16) Cand { double v; double u; int j; int row; };  // +urow folded in

// DPP lexicographic-min (val,idx): incoming lanes aggregate strictly-lower
// column ranges -> (tv <= bv) == first-index tie-break. Identity {+inf, MAX}.
template<int CTRL>
__device__ __forceinline__ void dpp_lexmin(double& bv, int& bj) {
    int lo = __double2loint(bv), hi = __double2hiint(bv);
    int tlo = __builtin_amdgcn_update_dpp(0, lo, CTRL, 0xF, 0xF, false);
    int thi = __builtin_amdgcn_update_dpp(0x7FF00000, hi, CTRL, 0xF, 0xF, false);
    int tj  = __builtin_amdgcn_update_dpp(0x7FFFFFFF, bj, CTRL, 0xF, 0xF, false);
    double tv = __hiloint2double(thi, tlo);
    if (tv <= bv) { bv = tv; bj = tj; }
}

// f32 wave-min step: 2 instr/stage (update_dpp + v_min_f32). Identity +INF.
template<int CTRL>
__device__ __forceinline__ float dpp_minf(float v) {
    int t = __builtin_amdgcn_update_dpp(0x7F800000, __float_as_int(v), CTRL, 0xF, 0xF, false);
    return fminf(v, __int_as_float(t));
}

// ---------------------------------------------------------------------------
// Kernel 1: producers. 512 blocks x 1024 threads, one 128-token cost tile per
// block, 8 threads/token (o-sixteenths), 16-iter cost loop. 46.5 KB LDS ->
// 2 blocks/CU (32 waves/CU) -> 8 waves/SIMD = FULL occupancy (was 4 at
// NTP=512). Producer is latency-bound (r8 instruction trims: -1.8us; r9
// occupancy 2->4 waves/SIMD: -4.7us), so the last doubling is the remaining
// lever. Wave w covers token-half (w&1, tid bit 6 - same as r9) and
// o-sixteenth (w>>1); per-o partials rmin[o*2+(w&1)] come from the identical
// 64-token sets -> rowmins content BYTE-IDENTICAL to r9 -> LSA untouched.
// XCD mapping: b = bx&31 keeps batch b's tiles and its LSA block on one XCD.
// ---------------------------------------------------------------------------
struct SMC {
    float  xv[TPT * CPAD];                     // 41472 B
    float4 box[OO];                            // {x1,y1,x2,y2}
    float2 wt[OO];                             // {w2h2, tc-as-float-bits}
    u64    rmin[OO * 2];                       // per-token-half packed (m1|j1)
    float  ms[TPT];                            // per-token softmax max
    float  lsv[TPT];                           // per-token log-sum
};

__global__ __launch_bounds__(NTP) void hung_cost_kernel(
    const float* __restrict__ pb, const float* __restrict__ tb,
    const float* __restrict__ cls, const int* __restrict__ tcls,
    float* __restrict__ cost, u64* __restrict__ rowmins) {
#pragma clang fp contract(off)
    __shared__ SMC sm;

    int bx = blockIdx.x;
    int b = bx & 31;
    int tile = bx >> 5;
    int t0 = tile * TPT;
    int tid = threadIdx.x;
    int lane = tid & 63;
    int wave = tid >> 6;         // 0..15
    int tok = tid & (TPT - 1);   // token: wave&1 selects half, lane selects slot
    int oe = tid >> 7;           // o-sixteenth: o in [oe*16, oe*16+16)

    // stage class tile (nontemporal: read-once); 2560 vf4 loads over 1024
    // threads -> guarded flat loop (2-3 iters/thread)
    const float* cbase = cls + ((size_t)b * TT + t0) * CC;
    for (int idx4 = tid * 4; idx4 < TPT * CC; idx4 += NTP * 4) {
        vf4 vv = __builtin_nontemporal_load((const vf4*)(cbase + idx4));
        int r = idx4 / CC;
        int c = idx4 - r * CC;
        float* dst = &sm.xv[r * CPAD + c];
        dst[0] = vv.x; dst[1] = vv.y; dst[2] = vv.z; dst[3] = vv.w;
    }
    if (tid < OO) {
        float4 tbox = ((const float4*)tb)[b * OO + tid];
        float x1 = tbox.x - tbox.z / 2.f;
        float y1 = tbox.y - tbox.w / 2.f;
        float x2 = tbox.x + tbox.z / 2.f;
        float y2 = tbox.y + tbox.w / 2.f;
        float4 bb; bb.x = x1; bb.y = y1; bb.z = x2; bb.w = y2;
        sm.box[tid] = bb;
        float w2 = x2 - x1;
        float h2 = (y2 - y1) + EPSF;
        float2 wt; wt.x = w2 * h2;
        wt.y = __int_as_float(tcls[b * OO + tid]);
        sm.wt[tid] = wt;
    }
    __syncthreads();

    // softmax normalizers, ONCE per token (threads 0-127; sequential op order
    // verbatim -> bit-identical to ref)
    if (tid < TPT) {
        const float* xr2 = &sm.xv[tid * CPAD];
        float m2 = xr2[0];
        #pragma unroll
        for (int c = 1; c < CC; ++c) m2 = fmaxf(m2, xr2[c]);
        float ssum = 0.f;
        #pragma unroll
        for (int c = 0; c < CC; ++c) ssum += expf(xr2[c] - m2);
        sm.ms[tid] = m2;
        sm.lsv[tid] = logf(ssum);
    }

    size_t bt = (size_t)b * TT + t0 + tok;
    float4 pbox = ((const float4*)pb)[bt];
    float b1x1 = pbox.x - pbox.z / 2.f;
    float b1y1 = pbox.y - pbox.w / 2.f;
    float b1x2 = pbox.x + pbox.z / 2.f;
    float b1y2 = pbox.y + pbox.w / 2.f;
    float w1 = b1x2 - b1x1;
    float h1 = (b1y2 - b1y1) + EPSF;
    float w1h1 = w1 * h1;
    __syncthreads();

    const float* xr = &sm.xv[tok * CPAD];
    float m = sm.ms[tok];       // 8-way LDS broadcast (free)
    float ls = sm.lsv[tok];

    int colbase = t0 + ((wave & 1) << 6);   // this wave's token base
    float* cw = cost + (size_t)b * OO * TT + (size_t)(oe * (OO / 8)) * TT + t0 + tok;
    for (int k = 0; k < OO / 8; ++k) {      // 16 iters
        int o = oe * (OO / 8) + k;
        float4 bb = sm.box[o];          // one b128 broadcast per wave
        float2 wt = sm.wt[o];
        float b2x1 = bb.x, b2y1 = bb.y, b2x2 = bb.z, b2y2 = bb.w;
        float iw = fminf(b1x2, b2x2) - fmaxf(b1x1, b2x1);
        float ih = fminf(b1y2, b2y2) - fmaxf(b1y1, b2y1);
        iw = fmaxf(iw, 0.f);
        ih = fmaxf(ih, 0.f);
        float inter = iw * ih;
        float uni = ((w1h1 + wt.x) - inter) + EPSF;
        float iou = inter / uni;
        float cw2 = fmaxf(b1x2, b2x2) - fminf(b1x1, b2x1);
        float ch = fmaxf(b1y2, b2y2) - fminf(b1y1, b2y1);
        float c_area = (cw2 * ch) + EPSF;
        float giou = iou - (c_area - uni) / c_area;
        float bbox_loss = 1.0f - giou;

        float xc = xr[__float_as_int(wt.y)];   // conflict-free (stride 81)
        float shifted = xc - m;
        float cls_neg = -(shifted - ls);

        float cval = bbox_loss + cls_neg;
        *cw = cval;
        cw += TT;

        // wave min via f32 fminf-DPP, argmin via ballot (lowest lane = lowest col)
        float bvv = cval;
        bvv = dpp_minf<0x111>(bvv);
        bvv = dpp_minf<0x112>(bvv);
        bvv = dpp_minf<0x114>(bvv);
        bvv = dpp_minf<0x118>(bvv);
        bvv = dpp_minf<0x142>(bvv);
        bvv = dpp_minf<0x143>(bvv);
        float mv = __int_as_float(__builtin_amdgcn_readlane(__float_as_int(bvv), 63));
        unsigned long long msk = __ballot(cval == mv);
        int col = colbase + (__ffsll((long long)msk) - 1);
        if (lane == 63)
            sm.rmin[o * 2 + (wave & 1)] =
                ((u64)__float_as_uint(mv) << 32) | (unsigned)col;
    }
    __syncthreads();
    if (tid < OO) {
        u64 r0 = sm.rmin[tid * 2 + 0];
        u64 r1 = sm.rmin[tid * 2 + 1];
        rowmins[((size_t)b * NTILE + tile) * OO + tid] = r0 < r1 ? r0 : r1;
    }
    // No release protocol: kernel boundary on the stream is the fence.
}

// ---------------------------------------------------------------------------
// Kernel 2: JV LSA, 32 blocks (one per batch), VERBATIM the verified
// round-3/7/8/9 kernel (measured 138.5-139 us; r4 LDS-cache, r6 wave0-SAP
// and r2 auction all regressed -> this 4-wave structure is at its latency
// floor: ~950 cyc/iteration serial chain x ~350 iterations on the max batch).
// ---------------------------------------------------------------------------
struct SML {
    URow   urow[TT];
    P2     path2[TT];                          // swizzled
    int    row4col[TT];
    int    claim[TT];
    int    col4row[OO];
    double u[OO];
    int    amin[OO];
    int    flag[OO];
    int    freelist[OO];
    int    selj[OO + 8];
    double selm[OO + 8];
    int    selrow[OO + 8];
    Cand   cand[2][4];
    int    nfree;
};

__global__ __launch_bounds__(NT) void hung_lsa_kernel(
    const float* __restrict__ cost,
    const u64* __restrict__ rowmins,
    int* __restrict__ out) {
#pragma clang fp contract(off)
    __shared__ SML sm;

    int b = blockIdx.x;
    int tid = threadIdx.x;
    int lane = tid & 63;
    int wave = tid >> 6;

    const float* cb = cost + (size_t)b * OO * TT;
    const int jbase = tid * SLOTS;

    double v_[SLOTS];
    double key[SLOTS];
    #pragma unroll
    for (int s = 0; s < SLOTS; ++s) v_[s] = 0.0;

    // ---- Phase A: u = row minima (combine the 16 tile results) ----
    if (tid < OO) {
        const u64* p = rowmins + (size_t)b * NTILE * OO + tid;
        u64 best = p[0];
        #pragma unroll
        for (int t = 1; t < NTILE; ++t) {
            u64 x = p[t * OO];
            if (x < best) best = x;
        }
        sm.u[tid] = (double)__uint_as_float((unsigned)(best >> 32));
        sm.amin[tid] = (int)(best & 0xFFFFFFFFull);
        sm.col4row[tid] = -1;
    }
    for (int j = tid; j < TT; j += NT) { sm.row4col[j] = -1; sm.claim[j] = 0x7FFFFFFF; }
    __syncthreads();

    // ---- Phase B: greedy tight pre-assignment (lowest row wins) ----
    if (tid < OO) atomicMin(&sm.claim[sm.amin[tid]], tid);
    __syncthreads();
    if (tid < OO) {
        int j = sm.amin[tid];
        if (sm.claim[j] == tid) { sm.col4row[tid] = j; sm.row4col[j] = tid; }
    }
    __syncthreads();

    // ---- Phase C: urow init + free-row list ----
    for (int j = tid; j < TT; j += NT) {
        int r = sm.row4col[j];
        URow t; t.row = r; t.u = (r >= 0) ? sm.u[r] : 0.0; t.pad = 0;
        sm.urow[j] = t;
    }
    if (tid < OO) sm.flag[tid] = (sm.col4row[tid] < 0) ? 1 : 0;
    __syncthreads();
    if (tid < OO && sm.flag[tid]) {
        int rank = 0;
        for (int o = 0; o < tid; ++o) rank += sm.flag[o];
        sm.freelist[rank] = tid;
    }
    if (tid == 0) {
        int nf = 0;
        for (int o = 0; o < OO; ++o) nf += sm.flag[o];
        sm.nfree = nf;
    }
    __syncthreads();
    int nfree = sm.nfree;

    // root-row prefetch for the first Dijkstra
    float4 pf0, pf1;
    if (nfree > 0) {
        const float* rr = cb + (size_t)sm.freelist[0] * TT + jbase;
        pf0 = *(const float4*)rr;
        pf1 = *(const float4*)(rr + 4);
    }

    // ---- Phase D: Dijkstra SAP ----
    int par = 0;
    for (int fi = 0; fi < nfree; ++fi) {
        int cur = sm.freelist[fi];

        #pragma unroll
        for (int s = 0; s < SLOTS; ++s) key[s] = INFINITY;
        int selbits = 0;
        double mv = 0.0;
        int i = cur, jc = -1;
        double ui = sm.u[cur];
        float4 c0 = pf0, c1 = pf1;
        int L = 0, sink;

        while (true) {
            float cv[SLOTS] = {c0.x, c0.y, c0.z, c0.w, c1.x, c1.y, c1.z, c1.w};
            double D = ui - mv;   // wave-uniform; one dependent op hoisted

            double bv = INFINITY;
            int bj = TT;
            #pragma unroll
            for (int s = 0; s < SLOTS; ++s) {
                if (!((selbits >> s) & 1)) {
                    double r = ((double)cv[s] - D) - v_[s];
                    if (r < key[s]) {
                        key[s] = r;
                        P2 p; p.i = i; p.j = jc;
                        sm.path2[s * NT + tid] = p;
                    }
                    double kk = key[s];
                    if (kk < bv) { bv = kk; bj = jbase + s; }
                }
            }
            dpp_lexmin<0x111>(bv, bj);
            dpp_lexmin<0x112>(bv, bj);
            dpp_lexmin<0x114>(bv, bj);
            dpp_lexmin<0x118>(bv, bj);
            dpp_lexmin<0x142>(bv, bj);
            dpp_lexmin<0x143>(bv, bj);
            int rlo = __builtin_amdgcn_readlane(__double2loint(bv), 63);
            int rhi = __builtin_amdgcn_readlane(__double2hiint(bv), 63);
            double wv = __hiloint2double(rhi, rlo);
            int wj = __builtin_amdgcn_readlane(bj, 63);

            // Pre-barrier urow fold-in: each wave reads its own candidate's
            // urow entry (read-only during the while loop); the LDS latency
            // overlaps other waves' barrier arrival.
            URow uwv = sm.urow[wj];            // wave-uniform b128 read

            par ^= 1;
            if (lane == 0) {
                Cand c; c.v = wv; c.u = uwv.u; c.j = wj; c.row = uwv.row;
                sm.cand[par][wave] = c;
            }
            __syncthreads();

            Cand cc0 = sm.cand[par][0];
            Cand cc1 = sm.cand[par][1];
            Cand cc2 = sm.cand[par][2];
            Cand cc3 = sm.cand[par][3];
            double MV = cc0.v; int BJ = cc0.j; int WR = cc0.row; double WU = cc0.u;
            if (cc1.v < MV || (cc1.v == MV && cc1.j < BJ)) { MV = cc1.v; BJ = cc1.j; WR = cc1.row; WU = cc1.u; }
            if (cc2.v < MV || (cc2.v == MV && cc2.j < BJ)) { MV = cc2.v; BJ = cc2.j; WR = cc2.row; WU = cc2.u; }
            if (cc3.v < MV || (cc3.v == MV && cc3.j < BJ)) { MV = cc3.v; BJ = cc3.j; WR = cc3.row; WU = cc3.u; }
            mv = MV;
            if ((BJ >> 3) == tid) selbits |= 1 << (BJ & 7);
            if (tid == 0) sm.selj[L] = BJ;

            if (WR < 0) { sink = BJ; break; }
            if (tid == 0) { sm.selm[L] = MV; sm.selrow[L] = WR; }
            i = WR; ui = WU; jc = BJ;
            L++;
            const float* crow = cb + (size_t)i * TT + jbase;
            c0 = *(const float4*)crow;
            c1 = *(const float4*)(crow + 4);
        }

        // prefetch next Dijkstra's root row (off the critical path)
        if (fi + 1 < nfree) {
            const float* rr = cb + (size_t)sm.freelist[fi + 1] * TT + jbase;
            pf0 = *(const float4*)rr;
            pf1 = *(const float4*)(rr + 4);
        }

        double M = mv;
        #pragma unroll
        for (int s = 0; s < SLOTS; ++s)
            if ((selbits >> s) & 1) v_[s] = v_[s] - (M - key[s]);
        for (int k = tid; k < L; k += NT)
            sm.u[sm.selrow[k]] = sm.u[sm.selrow[k]] + (M - sm.selm[k]);
        if (tid == 0) {
            sm.u[cur] = sm.u[cur] + M;
            int j = sink;
            while (true) {
                P2 p = sm.path2[(j & 7) * NT + (j >> 3)];
                int ii = p.i;
                sm.row4col[j] = ii;
                sm.col4row[ii] = j;
                if (ii == cur) break;
                j = p.j;
            }
        }
        __syncthreads();
        if (tid <= L) {
            int j = sm.selj[tid];
            int r = sm.row4col[j];
            URow t; t.u = sm.u[r]; t.row = r; t.pad = 0;
            sm.urow[j] = t;
        }
        __syncthreads();
    }

    // order = argsort(col4row); pred_idx = col4row[order]; tgt_idx = order
    if (tid < OO) {
        int my = sm.col4row[tid];
        int rank = 0;
        for (int o = 0; o < OO; ++o) rank += (sm.col4row[o] < my) ? 1 : 0;
        out[(size_t)b * OO + rank] = my;         // pred_idx
        out[(size_t)(BB + b) * OO + rank] = tid; // tgt_idx
    }
}

// ---------------------------------------------------------------------------
extern "C" void kernel_launch(void* const* d_in, const int* in_sizes, int n_in,
                              void* d_out, int out_size, void* d_ws, size_t ws_size,
                              hipStream_t stream) {
    const float* pred_bboxes = (const float*)d_in[0];    // [B,T,4]
    const float* target_bboxes = (const float*)d_in[1];  // [B,O,4]
    const float* pred_classes = (const float*)d_in[2];   // [B,T,C]
    const int* target_classes = (const int*)d_in[3];     // [B,O]
    int* out = (int*)d_out;                              // [2,B,O] int32

    float* cost = (float*)d_ws;  // [B][O][T] fp32 (32 MB)
    u64* rowmins = (u64*)(cost + (size_t)BB * OO * TT);  // [B][NTILE][O]

    hung_cost_kernel<<<BB * NTILE, NTP, 0, stream>>>(
        pred_bboxes, target_bboxes, pred_classes, target_classes, cost, rowmins);
    hung_lsa_kernel<<<BB, NT, 0, stream>>>(cost, rowmins, out);
}

// Round 11
// 234.482 us; speedup vs baseline: 1.0172x; 1.0172x over previous
//
#include <hip/hip_runtime.h>
#include <math.h>
#include <float.h>

// Problem dims (fixed by setup_inputs)
#define BB 32
#define TT 2048
#define OO 128
#define CC 80
#define EPSF 1e-7f
#define NT 256            // LSA block size
#define NTP 512           // producer block size (4 thr/token -> 4 waves/SIMD: MEASURED optimum; 1024 (8 w/SIMD) regressed -3.9us in r10 — prologue duplication beats latency hiding)
#define SLOTS 8           // columns per thread in LSA
#define CPAD 81           // LDS class-row stride: 81%32=17, gcd(17,32)=1 -> conflict-free
#define TPT 128           // tokens per cost tile
#define NTILE 16          // cost t-tiles (TT/TPT)

typedef float vf4 __attribute__((ext_vector_type(4)));   // native vec for nontemporal
typedef unsigned long long u64;

struct alignas(16) URow { double u; int row; int pad; };   // {u[row4col[j]], row4col[j]}
struct alignas(8)  P2   { int i; int j; };                 // path row, its prior column
struct alignas(16) Cand { double v; double u; int j; int row; };  // +urow folded in

// DPP lexicographic-min (val,idx): incoming lanes aggregate strictly-lower
// column ranges -> (tv <= bv) == first-index tie-break. Identity {+inf, MAX}.
template<int CTRL>
__device__ __forceinline__ void dpp_lexmin(double& bv, int& bj) {
    int lo = __double2loint(bv), hi = __double2hiint(bv);
    int tlo = __builtin_amdgcn_update_dpp(0, lo, CTRL, 0xF, 0xF, false);
    int thi = __builtin_amdgcn_update_dpp(0x7FF00000, hi, CTRL, 0xF, 0xF, false);
    int tj  = __builtin_amdgcn_update_dpp(0x7FFFFFFF, bj, CTRL, 0xF, 0xF, false);
    double tv = __hiloint2double(thi, tlo);
    if (tv <= bv) { bv = tv; bj = tj; }
}

// f32 wave-min step: 2 instr/stage (update_dpp + v_min_f32). Identity +INF.
template<int CTRL>
__device__ __forceinline__ float dpp_minf(float v) {
    int t = __builtin_amdgcn_update_dpp(0x7F800000, __float_as_int(v), CTRL, 0xF, 0xF, false);
    return fminf(v, __int_as_float(t));
}

// ---------------------------------------------------------------------------
// Kernel 1: producers. 512 blocks x 512 threads, one 128-token cost tile per
// block, 4 threads/token (o-quarters), 32-iter cost loop. 46.5 KB LDS ->
// 2 blocks/CU -> 4 waves/SIMD resident — the MEASURED occupancy optimum
// (r8: NT=256/2 w/SIMD = 241.1; r9: 512/4 w/SIMD = 234.6; r10: 1024/8 w/SIMD
// = 238.5). Wave w covers token-half (w&1) and o-quarter (w>>1); per-o
// partials rmin[o*2+(w&1)] and the combine are bit-identical across these
// configs -> rowmins layout/content unchanged -> LSA kernel untouched.
// XCD mapping: b = bx&31 keeps batch b's tiles and its LSA block on one XCD.
// ---------------------------------------------------------------------------
struct SMC {
    float  xv[TPT * CPAD];                     // 41472 B
    float4 box[OO];                            // {x1,y1,x2,y2}
    float2 wt[OO];                             // {w2h2, tc-as-float-bits}
    u64    rmin[OO * 2];                       // per-token-half packed (m1|j1)
    float  ms[TPT];                            // per-token softmax max
    float  lsv[TPT];                           // per-token log-sum
};

__global__ __launch_bounds__(NTP) void hung_cost_kernel(
    const float* __restrict__ pb, const float* __restrict__ tb,
    const float* __restrict__ cls, const int* __restrict__ tcls,
    float* __restrict__ cost, u64* __restrict__ rowmins) {
#pragma clang fp contract(off)
    __shared__ SMC sm;

    int bx = blockIdx.x;
    int b = bx & 31;
    int tile = bx >> 5;
    int t0 = tile * TPT;
    int tid = threadIdx.x;
    int lane = tid & 63;
    int wave = tid >> 6;         // 0..7
    int tok = tid & (TPT - 1);   // token: wave&1 selects half, lane selects slot
    int oq = tid >> 7;           // o-quarter: o in [oq*32, oq*32+32)

    // stage class tile (nontemporal: read-once)
    const float* cbase = cls + ((size_t)b * TT + t0) * CC;
    #pragma unroll
    for (int k = 0; k < (TPT * CC) / (NTP * 4); ++k) {   // 5 iters
        int idx4 = (k * NTP + tid) * 4;
        vf4 vv = __builtin_nontemporal_load((const vf4*)(cbase + idx4));
        int r = idx4 / CC;
        int c = idx4 - r * CC;
        float* dst = &sm.xv[r * CPAD + c];
        dst[0] = vv.x; dst[1] = vv.y; dst[2] = vv.z; dst[3] = vv.w;
    }
    if (tid < OO) {
        float4 tbox = ((const float4*)tb)[b * OO + tid];
        float x1 = tbox.x - tbox.z / 2.f;
        float y1 = tbox.y - tbox.w / 2.f;
        float x2 = tbox.x + tbox.z / 2.f;
        float y2 = tbox.y + tbox.w / 2.f;
        float4 bb; bb.x = x1; bb.y = y1; bb.z = x2; bb.w = y2;
        sm.box[tid] = bb;
        float w2 = x2 - x1;
        float h2 = (y2 - y1) + EPSF;
        float2 wt; wt.x = w2 * h2;
        wt.y = __int_as_float(tcls[b * OO + tid]);
        sm.wt[tid] = wt;
    }
    __syncthreads();

    // softmax normalizers, ONCE per token (threads 0-127; sequential op order
    // verbatim -> bit-identical to ref)
    if (tid < TPT) {
        const float* xr2 = &sm.xv[tid * CPAD];
        float m2 = xr2[0];
        #pragma unroll
        for (int c = 1; c < CC; ++c) m2 = fmaxf(m2, xr2[c]);
        float ssum = 0.f;
        #pragma unroll
        for (int c = 0; c < CC; ++c) ssum += expf(xr2[c] - m2);
        sm.ms[tid] = m2;
        sm.lsv[tid] = logf(ssum);
    }

    size_t bt = (size_t)b * TT + t0 + tok;
    float4 pbox = ((const float4*)pb)[bt];
    float b1x1 = pbox.x - pbox.z / 2.f;
    float b1y1 = pbox.y - pbox.w / 2.f;
    float b1x2 = pbox.x + pbox.z / 2.f;
    float b1y2 = pbox.y + pbox.w / 2.f;
    float w1 = b1x2 - b1x1;
    float h1 = (b1y2 - b1y1) + EPSF;
    float w1h1 = w1 * h1;
    __syncthreads();

    const float* xr = &sm.xv[tok * CPAD];
    float m = sm.ms[tok];       // 4-way LDS broadcast (free)
    float ls = sm.lsv[tok];

    int colbase = t0 + ((wave & 1) << 6);   // this wave's token base
    float* cw = cost + (size_t)b * OO * TT + (size_t)(oq * (OO / 4)) * TT + t0 + tok;
    for (int k = 0; k < OO / 4; ++k) {      // 32 iters
        int o = oq * (OO / 4) + k;
        float4 bb = sm.box[o];          // one b128 broadcast per wave
        float2 wt = sm.wt[o];
        float b2x1 = bb.x, b2y1 = bb.y, b2x2 = bb.z, b2y2 = bb.w;
        float iw = fminf(b1x2, b2x2) - fmaxf(b1x1, b2x1);
        float ih = fminf(b1y2, b2y2) - fmaxf(b1y1, b2y1);
        iw = fmaxf(iw, 0.f);
        ih = fmaxf(ih, 0.f);
        float inter = iw * ih;
        float uni = ((w1h1 + wt.x) - inter) + EPSF;
        float iou = inter / uni;
        float cw2 = fmaxf(b1x2, b2x2) - fminf(b1x1, b2x1);
        float ch = fmaxf(b1y2, b2y2) - fminf(b1y1, b2y1);
        float c_area = (cw2 * ch) + EPSF;
        float giou = iou - (c_area - uni) / c_area;
        float bbox_loss = 1.0f - giou;

        float xc = xr[__float_as_int(wt.y)];   // conflict-free (stride 81)
        float shifted = xc - m;
        float cls_neg = -(shifted - ls);

        float cval = bbox_loss + cls_neg;
        *cw = cval;
        cw += TT;

        // wave min via f32 fminf-DPP, argmin via ballot (lowest lane = lowest col)
        float bvv = cval;
        bvv = dpp_minf<0x111>(bvv);
        bvv = dpp_minf<0x112>(bvv);
        bvv = dpp_minf<0x114>(bvv);
        bvv = dpp_minf<0x118>(bvv);
        bvv = dpp_minf<0x142>(bvv);
        bvv = dpp_minf<0x143>(bvv);
        float mv = __int_as_float(__builtin_amdgcn_readlane(__float_as_int(bvv), 63));
        unsigned long long msk = __ballot(cval == mv);
        int col = colbase + (__ffsll((long long)msk) - 1);
        if (lane == 63)
            sm.rmin[o * 2 + (wave & 1)] =
                ((u64)__float_as_uint(mv) << 32) | (unsigned)col;
    }
    __syncthreads();
    if (tid < OO) {
        u64 r0 = sm.rmin[tid * 2 + 0];
        u64 r1 = sm.rmin[tid * 2 + 1];
        rowmins[((size_t)b * NTILE + tile) * OO + tid] = r0 < r1 ? r0 : r1;
    }
    // No release protocol: kernel boundary on the stream is the fence.
}

// ---------------------------------------------------------------------------
// Kernel 2: JV LSA, 32 blocks (one per batch), VERBATIM the verified
// round-3/7/8/9 kernel (measured 138.5-139 us; r4 LDS-cache, r6 wave0-SAP
// and r2 auction all regressed -> this 4-wave structure is at its latency
// floor: ~950 cyc/iteration serial chain x ~350 iterations on the max batch).
// ---------------------------------------------------------------------------
struct SML {
    URow   urow[TT];
    P2     path2[TT];                          // swizzled
    int    row4col[TT];
    int    claim[TT];
    int    col4row[OO];
    double u[OO];
    int    amin[OO];
    int    flag[OO];
    int    freelist[OO];
    int    selj[OO + 8];
    double selm[OO + 8];
    int    selrow[OO + 8];
    Cand   cand[2][4];
    int    nfree;
};

__global__ __launch_bounds__(NT) void hung_lsa_kernel(
    const float* __restrict__ cost,
    const u64* __restrict__ rowmins,
    int* __restrict__ out) {
#pragma clang fp contract(off)
    __shared__ SML sm;

    int b = blockIdx.x;
    int tid = threadIdx.x;
    int lane = tid & 63;
    int wave = tid >> 6;

    const float* cb = cost + (size_t)b * OO * TT;
    const int jbase = tid * SLOTS;

    double v_[SLOTS];
    double key[SLOTS];
    #pragma unroll
    for (int s = 0; s < SLOTS; ++s) v_[s] = 0.0;

    // ---- Phase A: u = row minima (combine the 16 tile results) ----
    if (tid < OO) {
        const u64* p = rowmins + (size_t)b * NTILE * OO + tid;
        u64 best = p[0];
        #pragma unroll
        for (int t = 1; t < NTILE; ++t) {
            u64 x = p[t * OO];
            if (x < best) best = x;
        }
        sm.u[tid] = (double)__uint_as_float((unsigned)(best >> 32));
        sm.amin[tid] = (int)(best & 0xFFFFFFFFull);
        sm.col4row[tid] = -1;
    }
    for (int j = tid; j < TT; j += NT) { sm.row4col[j] = -1; sm.claim[j] = 0x7FFFFFFF; }
    __syncthreads();

    // ---- Phase B: greedy tight pre-assignment (lowest row wins) ----
    if (tid < OO) atomicMin(&sm.claim[sm.amin[tid]], tid);
    __syncthreads();
    if (tid < OO) {
        int j = sm.amin[tid];
        if (sm.claim[j] == tid) { sm.col4row[tid] = j; sm.row4col[j] = tid; }
    }
    __syncthreads();

    // ---- Phase C: urow init + free-row list ----
    for (int j = tid; j < TT; j += NT) {
        int r = sm.row4col[j];
        URow t; t.row = r; t.u = (r >= 0) ? sm.u[r] : 0.0; t.pad = 0;
        sm.urow[j] = t;
    }
    if (tid < OO) sm.flag[tid] = (sm.col4row[tid] < 0) ? 1 : 0;
    __syncthreads();
    if (tid < OO && sm.flag[tid]) {
        int rank = 0;
        for (int o = 0; o < tid; ++o) rank += sm.flag[o];
        sm.freelist[rank] = tid;
    }
    if (tid == 0) {
        int nf = 0;
        for (int o = 0; o < OO; ++o) nf += sm.flag[o];
        sm.nfree = nf;
    }
    __syncthreads();
    int nfree = sm.nfree;

    // root-row prefetch for the first Dijkstra
    float4 pf0, pf1;
    if (nfree > 0) {
        const float* rr = cb + (size_t)sm.freelist[0] * TT + jbase;
        pf0 = *(const float4*)rr;
        pf1 = *(const float4*)(rr + 4);
    }

    // ---- Phase D: Dijkstra SAP ----
    int par = 0;
    for (int fi = 0; fi < nfree; ++fi) {
        int cur = sm.freelist[fi];

        #pragma unroll
        for (int s = 0; s < SLOTS; ++s) key[s] = INFINITY;
        int selbits = 0;
        double mv = 0.0;
        int i = cur, jc = -1;
        double ui = sm.u[cur];
        float4 c0 = pf0, c1 = pf1;
        int L = 0, sink;

        while (true) {
            float cv[SLOTS] = {c0.x, c0.y, c0.z, c0.w, c1.x, c1.y, c1.z, c1.w};
            double D = ui - mv;   // wave-uniform; one dependent op hoisted

            double bv = INFINITY;
            int bj = TT;
            #pragma unroll
            for (int s = 0; s < SLOTS; ++s) {
                if (!((selbits >> s) & 1)) {
                    double r = ((double)cv[s] - D) - v_[s];
                    if (r < key[s]) {
                        key[s] = r;
                        P2 p; p.i = i; p.j = jc;
                        sm.path2[s * NT + tid] = p;
                    }
                    double kk = key[s];
                    if (kk < bv) { bv = kk; bj = jbase + s; }
                }
            }
            dpp_lexmin<0x111>(bv, bj);
            dpp_lexmin<0x112>(bv, bj);
            dpp_lexmin<0x114>(bv, bj);
            dpp_lexmin<0x118>(bv, bj);
            dpp_lexmin<0x142>(bv, bj);
            dpp_lexmin<0x143>(bv, bj);
            int rlo = __builtin_amdgcn_readlane(__double2loint(bv), 63);
            int rhi = __builtin_amdgcn_readlane(__double2hiint(bv), 63);
            double wv = __hiloint2double(rhi, rlo);
            int wj = __builtin_amdgcn_readlane(bj, 63);

            // Pre-barrier urow fold-in: each wave reads its own candidate's
            // urow entry (read-only during the while loop); the LDS latency
            // overlaps other waves' barrier arrival.
            URow uwv = sm.urow[wj];            // wave-uniform b128 read

            par ^= 1;
            if (lane == 0) {
                Cand c; c.v = wv; c.u = uwv.u; c.j = wj; c.row = uwv.row;
                sm.cand[par][wave] = c;
            }
            __syncthreads();

            Cand cc0 = sm.cand[par][0];
            Cand cc1 = sm.cand[par][1];
            Cand cc2 = sm.cand[par][2];
            Cand cc3 = sm.cand[par][3];
            double MV = cc0.v; int BJ = cc0.j; int WR = cc0.row; double WU = cc0.u;
            if (cc1.v < MV || (cc1.v == MV && cc1.j < BJ)) { MV = cc1.v; BJ = cc1.j; WR = cc1.row; WU = cc1.u; }
            if (cc2.v < MV || (cc2.v == MV && cc2.j < BJ)) { MV = cc2.v; BJ = cc2.j; WR = cc2.row; WU = cc2.u; }
            if (cc3.v < MV || (cc3.v == MV && cc3.j < BJ)) { MV = cc3.v; BJ = cc3.j; WR = cc3.row; WU = cc3.u; }
            mv = MV;
            if ((BJ >> 3) == tid) selbits |= 1 << (BJ & 7);
            if (tid == 0) sm.selj[L] = BJ;

            if (WR < 0) { sink = BJ; break; }
            if (tid == 0) { sm.selm[L] = MV; sm.selrow[L] = WR; }
            i = WR; ui = WU; jc = BJ;
            L++;
            const float* crow = cb + (size_t)i * TT + jbase;
            c0 = *(const float4*)crow;
            c1 = *(const float4*)(crow + 4);
        }

        // prefetch next Dijkstra's root row (off the critical path)
        if (fi + 1 < nfree) {
            const float* rr = cb + (size_t)sm.freelist[fi + 1] * TT + jbase;
            pf0 = *(const float4*)rr;
            pf1 = *(const float4*)(rr + 4);
        }

        double M = mv;
        #pragma unroll
        for (int s = 0; s < SLOTS; ++s)
            if ((selbits >> s) & 1) v_[s] = v_[s] - (M - key[s]);
        for (int k = tid; k < L; k += NT)
            sm.u[sm.selrow[k]] = sm.u[sm.selrow[k]] + (M - sm.selm[k]);
        if (tid == 0) {
            sm.u[cur] = sm.u[cur] + M;
            int j = sink;
            while (true) {
                P2 p = sm.path2[(j & 7) * NT + (j >> 3)];
                int ii = p.i;
                sm.row4col[j] = ii;
                sm.col4row[ii] = j;
                if (ii == cur) break;
                j = p.j;
            }
        }
        __syncthreads();
        if (tid <= L) {
            int j = sm.selj[tid];
            int r = sm.row4col[j];
            URow t; t.u = sm.u[r]; t.row = r; t.pad = 0;
            sm.urow[j] = t;
        }
        __syncthreads();
    }

    // order = argsort(col4row); pred_idx = col4row[order]; tgt_idx = order
    if (tid < OO) {
        int my = sm.col4row[tid];
        int rank = 0;
        for (int o = 0; o < OO; ++o) rank += (sm.col4row[o] < my) ? 1 : 0;
        out[(size_t)b * OO + rank] = my;         // pred_idx
        out[(size_t)(BB + b) * OO + rank] = tid; // tgt_idx
    }
}

// ---------------------------------------------------------------------------
extern "C" void kernel_launch(void* const* d_in, const int* in_sizes, int n_in,
                              void* d_out, int out_size, void* d_ws, size_t ws_size,
                              hipStream_t stream) {
    const float* pred_bboxes = (const float*)d_in[0];    // [B,T,4]
    const float* target_bboxes = (const float*)d_in[1];  // [B,O,4]
    const float* pred_classes = (const float*)d_in[2];   // [B,T,C]
    const int* target_classes = (const int*)d_in[3];     // [B,O]
    int* out = (int*)d_out;                              // [2,B,O] int32

    float* cost = (float*)d_ws;  // [B][O][T] fp32 (32 MB)
    u64* rowmins = (u64*)(cost + (size_t)BB * OO * TT);  // [B][NTILE][O]

    hung_cost_kernel<<<BB * NTILE, NTP, 0, stream>>>(
        pred_bboxes, target_bboxes, pred_classes, target_classes, cost, rowmins);
    hung_lsa_kernel<<<BB, NT, 0, stream>>>(cost, rowmins, out);
}